// Round 3
// baseline (183.007 us; speedup 1.0000x reference)
//
#include <hip/hip_runtime.h>

#define SAMPLES 128
#define HID 256
#define NEARV 0.1f
#define FARV 4.0f
#define DZ ((FARV - NEARV) / (SAMPLES - 1))
#define EPSV 1e-6f

typedef __attribute__((ext_vector_type(8))) short v8s;    // 8 x bf16
typedef __attribute__((ext_vector_type(4))) float v4f;    // 4 x fp32
typedef __attribute__((ext_vector_type(16))) float v16f;  // 16 x fp32

__device__ __forceinline__ unsigned short f2b(float f) {
  union { float f; unsigned u; } v; v.f = f;
  return (unsigned short)((v.u + 0x7fffu + ((v.u >> 16) & 1u)) >> 16);  // RNE
}

#if __has_builtin(__builtin_amdgcn_cvt_pk_bf16_f32)
typedef __bf16 bf2 __attribute__((ext_vector_type(2)));
__device__ __forceinline__ unsigned pk2(float a, float b) {
  union { bf2 v; unsigned u; } c;
  c.v = __builtin_amdgcn_cvt_pk_bf16_f32(a, b);
  return c.u;
}
#else
__device__ __forceinline__ unsigned pk2(float a, float b) {
  return (unsigned)f2b(a) | ((unsigned)f2b(b) << 16);
}
#endif

// Swizzled LDS address for the 128x256 bf16 activation buffer.
// 16B chunk column XOR'd with (m & 15): all access patterns <=2-way/bank.
__device__ __forceinline__ int haddr(int m, int k) {
  return m * 256 + ((((k >> 3) ^ (m & 15)) << 3) | (k & 7));
}

// Pack W2 (fp32 [K=256][N=256]) into bf16 32x32x16 A-operand fragment-linear
// layout: chunk ((nt*16 + ks)*2 + h)*32 + r32 holds
// W2[k = ks*16 + h*8 .. +8)][n = nt*32 + r32].
__global__ void pack_w2(const float* __restrict__ W2, unsigned short* __restrict__ out) {
  int t = blockIdx.x * 256 + threadIdx.x;   // 0..8191, one 16B chunk each
  int r32 = t & 31;
  int h   = (t >> 5) & 1;
  int ks  = (t >> 6) & 15;
  int nt  = t >> 10;
  int n  = nt * 32 + r32;
  int k0 = ks * 16 + h * 8;
#pragma unroll
  for (int j = 0; j < 8; ++j) out[t * 8 + j] = f2b(W2[(k0 + j) * 256 + n]);
}

// Pack head weights [Wsig | Wrgb(:256) | zeros] (K=256, N=16), 16x16x32 layout.
__global__ void pack_head(const float* __restrict__ Wsig, const float* __restrict__ Wrgb,
                          unsigned short* __restrict__ out) {
  int t = blockIdx.x * 256 + threadIdx.x;   // 0..511
  if (t >= 512) return;
  int n = t & 15, q = (t >> 4) & 3, kt = t >> 6;
  int k0 = kt * 32 + q * 8;
#pragma unroll
  for (int j = 0; j < 8; ++j) {
    int k = k0 + j;
    float v = 0.f;
    if (n == 0)      v = Wsig[k];
    else if (n < 4)  v = Wrgb[k * 3 + (n - 1)];
    out[t * 8 + j] = f2b(v);
  }
}

// One block per ray: 1024 threads = 16 waves, M=128 samples.
// (1024,4): 128-VGPR budget -> no spills. LDS 68KB.
__global__ __launch_bounds__(1024, 4) void render(
    const float* __restrict__ cam, const float* __restrict__ rayv,
    const float* __restrict__ W1, const float* __restrict__ b1,
    const float* __restrict__ b2, const float* __restrict__ bsig,
    const float* __restrict__ Wrgb, const float* __restrict__ brgb,
    const unsigned short* __restrict__ W2p, const unsigned short* __restrict__ Hdp,
    float* __restrict__ out) {
  __shared__ __align__(16) unsigned short smem[128 * 256 + 2048];  // 64KB act + 4KB head partials

  const int tid = threadIdx.x;
  const int ray = blockIdx.x;
  float* fbH = (float*)(smem + 128 * 256);   // [2][128][4] f32 head partials

  // ---- Layer 1 (rank-2): h1[m][n] = relu(u[n] + z_m * v[n]) -> LDS bf16 [m][k]
  {
    float rvx = rayv[ray * 3 + 0], rvy = rayv[ray * 3 + 1], rvz = rayv[ray * 3 + 2];
    float rn  = 1.0f / sqrtf(rvx * rvx + rvy * rvy + rvz * rvz);
    float rdx = rvx * rn, rdy = rvy * rn, rdz = rvz * rn;
    float cx = cam[ray * 3 + 0], cy = cam[ray * 3 + 1], cz = cam[ray * 3 + 2];

    int n4 = (tid & 63) * 4;     // 4 consecutive n per thread
    int m0 = tid >> 6;           // 0..15
    float4 wa = *(const float4*)(W1 + n4);
    float4 wb = *(const float4*)(W1 + 256 + n4);
    float4 wc = *(const float4*)(W1 + 512 + n4);
    float4 bb = *(const float4*)(b1 + n4);
    float4 u, v;
    u.x = bb.x + cx * wa.x + cy * wb.x + cz * wc.x;  v.x = rdx * wa.x + rdy * wb.x + rdz * wc.x;
    u.y = bb.y + cx * wa.y + cy * wb.y + cz * wc.y;  v.y = rdx * wa.y + rdy * wb.y + rdz * wc.y;
    u.z = bb.z + cx * wa.z + cy * wb.z + cz * wc.z;  v.z = rdx * wa.z + rdy * wb.z + rdz * wc.z;
    u.w = bb.w + cx * wa.w + cy * wb.w + cz * wc.w;  v.w = rdx * wa.w + rdy * wb.w + rdz * wc.w;
#pragma unroll
    for (int r = 0; r < 8; ++r) {
      int m = m0 + r * 16;
      float z = NEARV + DZ * (float)m;
      float h0 = fmaxf(u.x + z * v.x, 0.f);
      float h1 = fmaxf(u.y + z * v.y, 0.f);
      float h2 = fmaxf(u.z + z * v.z, 0.f);
      float h3 = fmaxf(u.w + z * v.w, 0.f);
      uint2 pk; pk.x = pk2(h0, h1); pk.y = pk2(h2, h3);
      *(uint2*)(smem + haddr(m, n4)) = pk;   // ds_write_b64, conflict-free
    }
  }
  __syncthreads();

  const int lane = tid & 63;
  const int wv   = tid >> 6;        // 0..15
  const int l31  = lane & 31;
  const int half = lane >> 5;
  const int nwv  = wv & 3;          // 4-way N split (2 tiles of 32 each)
  const int mwv  = wv >> 2;         // 4-way M split (1 tile of 32)
  const int m0b  = mwv * 32;

  // ---- Layer 2 GEMM (swapped, 32x32x16): C'[n][m] = W2^T @ h1^T
  // A = W2 frags (row index -> n), B = h1 from LDS (col index -> m).
  v16f acc0 = (v16f)(0.f), acc1 = (v16f)(0.f);
  const v8s* Ap = (const v8s*)W2p;
  const int abase = ((nwv * 2 * 16) * 2 + half) * 32 + l31;
#pragma unroll
  for (int ks = 0; ks < 16; ++ks) {
    v8s a0 = Ap[abase + ks * 64];           // coalesced 1KB/wave
    v8s a1 = Ap[abase + 1024 + ks * 64];
    v8s b  = *(const v8s*)(smem + haddr(m0b + l31, ks * 16 + half * 8));  // ds_read_b128
    acc0 = __builtin_amdgcn_mfma_f32_32x32x16_bf16(a0, b, acc0, 0, 0, 0);
    acc1 = __builtin_amdgcn_mfma_f32_32x32x16_bf16(a1, b, acc1, 0, 0, 0);
  }
  __syncthreads();   // all h1 reads done; smem reused for h2

  // ---- epilogue: lane holds C'[n][m = m0b + l31],
  // n = nwv*64 + nt*32 + 8*g + 4*half + (0..3) for acc reg group g.
  {
    const int m = m0b + l31;
    const int nbase = nwv * 64 + half * 4;
#pragma unroll
    for (int g = 0; g < 4; ++g) {
      {
        int nb = nbase + g * 8;
        float4 bias = *(const float4*)(b2 + nb);
        float w0 = fmaxf(acc0[g * 4 + 0] + bias.x, 0.f);
        float w1 = fmaxf(acc0[g * 4 + 1] + bias.y, 0.f);
        float w2 = fmaxf(acc0[g * 4 + 2] + bias.z, 0.f);
        float w3 = fmaxf(acc0[g * 4 + 3] + bias.w, 0.f);
        uint2 pk; pk.x = pk2(w0, w1); pk.y = pk2(w2, w3);
        *(uint2*)(smem + haddr(m, nb)) = pk;
      }
      {
        int nb = nbase + 32 + g * 8;
        float4 bias = *(const float4*)(b2 + nb);
        float w0 = fmaxf(acc1[g * 4 + 0] + bias.x, 0.f);
        float w1 = fmaxf(acc1[g * 4 + 1] + bias.y, 0.f);
        float w2 = fmaxf(acc1[g * 4 + 2] + bias.z, 0.f);
        float w3 = fmaxf(acc1[g * 4 + 3] + bias.w, 0.f);
        uint2 pk; pk.x = pk2(w0, w1); pk.y = pk2(w2, w3);
        *(uint2*)(smem + haddr(m, nb)) = pk;
      }
    }
  }
  __syncthreads();

  // ---- heads (16x16x32): o[m][c] = h2[m] . Hd[:,c], K split across wave halves
  {
    const int q = lane >> 4, l16 = lane & 15;
    const int khalf = wv >> 3;         // k-half
    const int mrow  = (wv & 7) * 16;   // 16 rows per wave
    const v8s* Hp = (const v8s*)Hdp;
    v4f hacc = (v4f)(0.f);
#pragma unroll
    for (int kl = 0; kl < 4; ++kl) {
      int kt = khalf * 4 + kl;
      v8s a = *(const v8s*)(smem + haddr(mrow + l16, kt * 32 + q * 8));
      v8s b = Hp[(kt * 4 + q) * 16 + l16];
      hacc = __builtin_amdgcn_mfma_f32_16x16x32_bf16(a, b, hacc, 0, 0, 0);
    }
    if (l16 < 4) {
#pragma unroll
      for (int r = 0; r < 4; ++r)
        fbH[khalf * 512 + (mrow + q * 4 + r) * 4 + l16] = hacc[r];
    }
  }
  __syncthreads();

  // ---- volume rendering tail: single wave, shuffle scan
  if (tid < 64) {
    float rvx = rayv[ray * 3 + 0], rvy = rayv[ray * 3 + 1], rvz = rayv[ray * 3 + 2];
    float rn  = 1.0f / sqrtf(rvx * rvx + rvy * rvy + rvz * rvz);
    float rdx = rvx * rn, rdy = rvy * rn, rdz = rvz * rn;
    float dw0 = brgb[0] - (rdx * Wrgb[768] + rdy * Wrgb[771] + rdz * Wrgb[774]);
    float dw1 = brgb[1] - (rdx * Wrgb[769] + rdy * Wrgb[772] + rdz * Wrgb[775]);
    float dw2 = brgb[2] - (rdx * Wrgb[770] + rdy * Wrgb[773] + rdz * Wrgb[776]);
    float bs = bsig[0];

    int m0 = tid * 2, m1 = m0 + 1;
    float s0 = fmaxf(fbH[m0 * 4] + fbH[512 + m0 * 4] + bs, 0.f);
    float s1 = fmaxf(fbH[m1 * 4] + fbH[512 + m1 * 4] + bs, 0.f);
    float a0 = 1.0f - __expf(-s0 * DZ);
    float a1 = (m1 == SAMPLES - 1) ? 1.0f : (1.0f - __expf(-s1 * DZ));
    float v0 = 1.0f - a0 + EPSV;
    float v1 = 1.0f - a1 + EPSV;

    float P = v0 * v1;
#pragma unroll
    for (int d = 1; d < 64; d <<= 1) {       // inclusive cumprod over lanes
      float t = __shfl_up(P, d);
      if (tid >= d) P *= t;
    }
    float E = __shfl_up(P, 1);               // exclusive
    if (tid == 0) E = 1.0f;
    float w0 = a0 * E;
    float w1 = a1 * E * v0;

    float dwc[3] = {dw0, dw1, dw2};
    float res[3];
#pragma unroll
    for (int c = 0; c < 3; ++c) {
      float x0 = fbH[m0 * 4 + 1 + c] + fbH[512 + m0 * 4 + 1 + c] + dwc[c];
      float x1 = fbH[m1 * 4 + 1 + c] + fbH[512 + m1 * 4 + 1 + c] + dwc[c];
      float r0 = 1.0f / (1.0f + __expf(-x0));
      float r1 = 1.0f / (1.0f + __expf(-x1));
      float s = w0 * r0 + w1 * r1;
#pragma unroll
      for (int d = 32; d >= 1; d >>= 1) s += __shfl_xor(s, d);
      res[c] = s;
    }
    if (tid == 0) {
      out[ray * 3 + 0] = res[0];
      out[ray * 3 + 1] = res[1];
      out[ray * 3 + 2] = res[2];
    }
  }
}

extern "C" void kernel_launch(void* const* d_in, const int* in_sizes, int n_in,
                              void* d_out, int out_size, void* d_ws, size_t ws_size,
                              hipStream_t stream) {
  const float* cam  = (const float*)d_in[0];
  const float* rayv = (const float*)d_in[1];
  const float* W1   = (const float*)d_in[2];
  const float* b1   = (const float*)d_in[3];
  const float* W2   = (const float*)d_in[4];
  const float* b2   = (const float*)d_in[5];
  const float* Wsig = (const float*)d_in[6];
  const float* bsig = (const float*)d_in[7];
  const float* Wrgb = (const float*)d_in[8];
  const float* brgb = (const float*)d_in[9];
  float* out = (float*)d_out;

  unsigned short* W2p = (unsigned short*)d_ws;     // 256*256 bf16 = 128 KB
  unsigned short* Hdp = W2p + 256 * 256;           // 256*16 bf16 = 8 KB

  int R = in_sizes[0] / 3;                         // B*N rays (4096)

  pack_w2<<<32, 256, 0, stream>>>(W2, W2p);
  pack_head<<<2, 256, 0, stream>>>(Wsig, Wrgb, Hdp);
  render<<<R, 1024, 0, stream>>>(cam, rayv, W1, b1, b2, bsig, Wrgb, brgb, W2p, Hdp, out);
}